// Round 5
// baseline (259.273 us; speedup 1.0000x reference)
//
#include <hip/hip_runtime.h>
#include <hip/hip_bf16.h>

#define B_  32
#define P_  2048
#define C_  19
#define D_  512
#define H_  4
#define DH_ 128
#define NROW (B_*P_)
#define CH_  76          // C_*H_
#define CHP_ 96          // padded K for out-GEMM (3x32)

typedef float f32x4 __attribute__((ext_vector_type(4)));
typedef short bf16x8 __attribute__((ext_vector_type(8)));
typedef short short4v __attribute__((ext_vector_type(4)));

__device__ __forceinline__ unsigned short f2bf(float f) {
  unsigned int u = __float_as_uint(f);
  u += 0x7FFFu + ((u >> 16) & 1u);   // RNE
  return (unsigned short)(u >> 16);
}

// ---- prep1: K/V = ce @ W^T + b  (f32) ------------------------------------
__global__ __launch_bounds__(256) void prep1(
    const float* __restrict__ ce,
    const float* __restrict__ Wk, const float* __restrict__ bk,
    const float* __restrict__ Wv, const float* __restrict__ bv,
    float* __restrict__ Kg, float* __restrict__ Vg)
{
  int g = blockIdx.x * 256 + threadIdx.x;
  if (g >= 2*C_*D_) return;
  int which = (g >= C_*D_) ? 1 : 0;
  int idx = which ? (g - C_*D_) : g;
  int c = idx >> 9;
  int n = idx & (D_-1);
  const float* w = (which ? Wv : Wk) + (size_t)n * D_;
  const float* e = ce + (size_t)c * D_;
  float s = 0.f;
  #pragma unroll 8
  for (int d = 0; d < D_; ++d) s = fmaf(e[d], w[d], s);
  s += (which ? bv : bk)[n];
  if (which) Vg[idx] = s; else Kg[idx] = s;
}

// ---- prep2: M~[80][512], U_t[512][96], s0[80] (r3-verbatim) ---------------
__global__ __launch_bounds__(512) void prep2(
    const float* __restrict__ Wq, const float* __restrict__ bq,
    const float* __restrict__ Wo,
    const float* __restrict__ Kg, const float* __restrict__ Vg,
    unsigned short* __restrict__ Mt, unsigned short* __restrict__ Ut,
    float* __restrict__ s0g)
{
  int ch = blockIdx.x;   // 0..95
  int m  = threadIdx.x;  // 0..511
  if (ch >= CH_) {
    if (ch < 80) { Mt[ch*D_ + m] = 0; if (m == 0) s0g[ch] = 0.f; }
    Ut[(size_t)m*CHP_ + ch] = 0;
    return;
  }
  int h = ch / C_, c = ch % C_;
  const float rs128 = 0.08838834764831843f;  // 1/sqrt(128)
  const float* Kr = Kg + c*D_ + h*DH_;
  const float* Vr = Vg + c*D_ + h*DH_;

  float macc = 0.f;
  #pragma unroll 4
  for (int dh = 0; dh < DH_; ++dh)
    macc = fmaf(Wq[(size_t)(h*DH_+dh)*D_ + m], Kr[dh], macc);
  Mt[ch*D_ + m] = f2bf(macc * rs128);

  float uacc = 0.f;
  const float* wor = Wo + (size_t)m*D_ + h*DH_;
  #pragma unroll 4
  for (int dh = 0; dh < DH_; ++dh)
    uacc = fmaf(wor[dh], Vr[dh], uacc);
  Ut[(size_t)m*CHP_ + ch] = f2bf(uacc);

  if (m == 0) {
    float sa = 0.f;
    const float* bqr = bq + h*DH_;
    for (int dh = 0; dh < DH_; ++dh) sa = fmaf(bqr[dh], Kr[dh], sa);
    s0g[ch] = sa * rs128;
  }
}

// ---- K1: S = x@M~^T (+s0) -> softmax -> WaG (bf16 [NROW][96]) -------------
// r3-proven phase 1/2 structure (ct-outer, af[] replaced by inline reload).
__global__ __launch_bounds__(256) void k1_scores(
    const float* __restrict__ x,
    const unsigned short* __restrict__ Mt,   // [80][512] bf16 rows 76..79 zero
    const float* __restrict__ s0g,           // [80]
    unsigned short* __restrict__ WaG)        // [NROW][96] bf16
{
  __shared__ float Sf[32][84];
  __shared__ unsigned short Wa[32][104];

  const int t    = threadIdx.x;
  const int wave = t >> 6;
  const int lane = t & 63;
  const int lhi  = lane >> 4;
  const int llo  = lane & 15;
  const int rg   = wave >> 1;
  const int cs   = wave & 1;
  const int row0 = blockIdx.x * 32;

  // phase 1: S-GEMM (K=512); cs=0 -> ct 0..2, cs=1 -> ct 3..4
  {
    const float* xr = x + (size_t)(row0 + rg*16 + llo)*D_ + lhi*8;
    const int nct = cs ? 2 : 3;
    const int ct0 = cs ? 3 : 0;
    for (int i = 0; i < nct; ++i) {
      int ct = ct0 + i;
      f32x4 sacc = (f32x4){0.f,0.f,0.f,0.f};
      const unsigned short* mrow = Mt + (size_t)(ct*16 + llo)*D_ + lhi*8;
      #pragma unroll
      for (int ks = 0; ks < 16; ++ks) {
        f32x4 v0 = *(const f32x4*)(xr + ks*32);
        f32x4 v1 = *(const f32x4*)(xr + ks*32 + 4);
        bf16x8 a;
        a[0]=(short)f2bf(v0[0]); a[1]=(short)f2bf(v0[1]);
        a[2]=(short)f2bf(v0[2]); a[3]=(short)f2bf(v0[3]);
        a[4]=(short)f2bf(v1[0]); a[5]=(short)f2bf(v1[1]);
        a[6]=(short)f2bf(v1[2]); a[7]=(short)f2bf(v1[3]);
        bf16x8 b = *(const bf16x8*)(mrow + ks*32);
        sacc = __builtin_amdgcn_mfma_f32_16x16x32_bf16(a, b, sacc, 0, 0, 0);
      }
      #pragma unroll
      for (int r = 0; r < 4; ++r)
        Sf[rg*16 + lhi*4 + r][ct*16 + llo] = sacc[r];
    }
  }
  __syncthreads();

  // phase 2: softmax over c per (row, h); zero pad cols 76..95
  if (t < 128) {
    int row = t >> 2, h = t & 3;
    float v[19];
    float mx = -1e30f;
    #pragma unroll
    for (int c = 0; c < C_; ++c) {
      v[c] = Sf[row][h*C_ + c] + s0g[h*C_ + c];
      mx = fmaxf(mx, v[c]);
    }
    float sum = 0.f;
    #pragma unroll
    for (int c = 0; c < C_; ++c) { float e = __expf(v[c] - mx); v[c] = e; sum += e; }
    float inv = 1.f / sum;
    #pragma unroll
    for (int c = 0; c < C_; ++c) Wa[row][h*C_ + c] = f2bf(v[c] * inv);
  } else {
    int t2 = t - 128;
    int row = t2 >> 2, g4 = t2 & 3;
    #pragma unroll
    for (int j = 0; j < 5; ++j) Wa[row][CH_ + g4*5 + j] = 0;
  }
  __syncthreads();

  // store Wa -> global, coalesced (12 shorts per thread)
  {
    int row = t >> 3;
    int col = (t & 7) * 12;
    unsigned short* dst = WaG + (size_t)(row0 + row)*CHP_ + col;
    #pragma unroll
    for (int u = 0; u < 3; ++u)
      *(short4v*)(dst + u*4) = *(const short4v*)&Wa[row][col + u*4];
  }
}

// ---- K2: out = Wa@U (+bo) + x, LN, store ----------------------------------
// phase 3 r3-verbatim orientation; epilogue via per-wave LDS transpose.
__global__ __launch_bounds__(256) void k2_out(
    const float* __restrict__ x,
    const unsigned short* __restrict__ WaG,  // [NROW][96] bf16
    const unsigned short* __restrict__ Ut,   // [512][96] bf16
    const float* __restrict__ bo,
    const float* __restrict__ gamma, const float* __restrict__ beta,
    float* __restrict__ out)
{
  __shared__ __attribute__((aligned(16))) float Tr[4][16][68];
  __shared__ float rs_[32][2], rq_[32][2];

  const int t    = threadIdx.x;
  const int wave = t >> 6;
  const int lane = t & 63;
  const int lhi  = lane >> 4;
  const int llo  = lane & 15;
  const int rg   = wave >> 1;
  const int cs   = wave & 1;
  const int row0 = blockIdx.x * 32;

  // out-GEMM (K=96): A = WaG rows (global, L2/L3-hot), B = Ut rows
  f32x4 oacc[16];
  #pragma unroll
  for (int i = 0; i < 16; ++i) oacc[i] = (f32x4){0.f,0.f,0.f,0.f};
  #pragma unroll
  for (int ks = 0; ks < 3; ++ks) {
    bf16x8 a = *(const bf16x8*)(WaG + (size_t)(row0 + rg*16 + llo)*CHP_ + ks*32 + lhi*8);
    #pragma unroll
    for (int tile = 0; tile < 16; ++tile) {
      int n = cs*256 + tile*16 + llo;
      bf16x8 b = *(const bf16x8*)(Ut + (size_t)n*CHP_ + ks*32 + lhi*8);
      oacc[tile] = __builtin_amdgcn_mfma_f32_16x16x32_bf16(a, b, oacc[tile], 0, 0, 0);
    }
  }
  // oacc[tile][r] = attn[m = rg*16 + lhi*4 + r][n = cs*256 + tile*16 + llo]

  // epilogue: per-wave LDS transpose -> lane owns one row, float4 cols
  const int rw = rg*16 + llo;
  const float* xrow = x + (size_t)(row0 + rw)*D_;
  float s = 0.f, q = 0.f;
  #pragma unroll
  for (int c2 = 0; c2 < 4; ++c2) {
    #pragma unroll
    for (int tl = 0; tl < 4; ++tl)
      #pragma unroll
      for (int r = 0; r < 4; ++r)
        Tr[wave][lhi*4 + r][tl*16 + llo] = oacc[c2*4 + tl][r];
    __syncthreads();
    #pragma unroll
    for (int j = 0; j < 4; ++j) {
      f32x4 v = *(const f32x4*)&Tr[wave][llo][j*16 + lhi*4];
      int n4 = cs*256 + c2*64 + j*16 + lhi*4;
      f32x4 xv = *(const f32x4*)(xrow + n4);
      f32x4 bv = *(const f32x4*)(bo + n4);
      f32x4 val = v + xv + bv;
      s += val[0] + val[1] + val[2] + val[3];
      q = fmaf(val[0], val[0], q); q = fmaf(val[1], val[1], q);
      q = fmaf(val[2], val[2], q); q = fmaf(val[3], val[3], q);
      oacc[c2*4 + j] = val;     // now: row rw, cols n4..n4+3
    }
    __syncthreads();
  }
  s += __shfl_xor(s, 16, 64);
  s += __shfl_xor(s, 32, 64);
  q += __shfl_xor(q, 16, 64);
  q += __shfl_xor(q, 32, 64);
  if (lhi == 0) { rs_[rw][cs] = s; rq_[rw][cs] = q; }
  __syncthreads();
  float sum = rs_[rw][0] + rs_[rw][1];
  float sq  = rq_[rw][0] + rq_[rw][1];
  float mu  = sum * (1.f/(float)D_);
  float var = sq * (1.f/(float)D_) - mu*mu;
  float rstd = rsqrtf(var + 1e-5f);
  float* orow = out + (size_t)(row0 + rw)*D_;
  #pragma unroll
  for (int c2 = 0; c2 < 4; ++c2) {
    #pragma unroll
    for (int j = 0; j < 4; ++j) {
      int n4 = cs*256 + c2*64 + j*16 + lhi*4;
      f32x4 gv = *(const f32x4*)(gamma + n4);
      f32x4 bt = *(const f32x4*)(beta + n4);
      f32x4 val = oacc[c2*4 + j];
      f32x4 o;
      o[0] = (val[0] - mu) * rstd * gv[0] + bt[0];
      o[1] = (val[1] - mu) * rstd * gv[1] + bt[1];
      o[2] = (val[2] - mu) * rstd * gv[2] + bt[2];
      o[3] = (val[3] - mu) * rstd * gv[3] + bt[3];
      *(f32x4*)(orow + n4) = o;
    }
  }
}

// ---- fallback: r3-verbatim fused kernel (if ws too small for WaG) --------
__global__ __launch_bounds__(256) void fused_main(
    const float* __restrict__ x,
    const unsigned short* __restrict__ Mt,
    const unsigned short* __restrict__ Ut,
    const float* __restrict__ s0g,
    const float* __restrict__ bo,
    const float* __restrict__ gamma, const float* __restrict__ beta,
    float* __restrict__ out)
{
  __shared__ float Sf[32][84];
  __shared__ unsigned short Wa[32][104];
  __shared__ float rs_[32][2], rq_[32][2];

  const int t    = threadIdx.x;
  const int wave = t >> 6;
  const int lane = t & 63;
  const int lhi  = lane >> 4;
  const int llo  = lane & 15;
  const int rg   = wave >> 1;
  const int cs   = wave & 1;
  const int row0 = blockIdx.x * 32;

  {
    const float* xr = x + (size_t)(row0 + rg*16 + llo)*D_ + lhi*8;
    const int nct = cs ? 2 : 3;
    const int ct0 = cs ? 3 : 0;
    for (int i = 0; i < nct; ++i) {
      int ct = ct0 + i;
      f32x4 sacc = (f32x4){0.f,0.f,0.f,0.f};
      const unsigned short* mrow = Mt + (size_t)(ct*16 + llo)*D_ + lhi*8;
      #pragma unroll
      for (int ks = 0; ks < 16; ++ks) {
        f32x4 v0 = *(const f32x4*)(xr + ks*32);
        f32x4 v1 = *(const f32x4*)(xr + ks*32 + 4);
        bf16x8 a;
        a[0]=(short)f2bf(v0[0]); a[1]=(short)f2bf(v0[1]);
        a[2]=(short)f2bf(v0[2]); a[3]=(short)f2bf(v0[3]);
        a[4]=(short)f2bf(v1[0]); a[5]=(short)f2bf(v1[1]);
        a[6]=(short)f2bf(v1[2]); a[7]=(short)f2bf(v1[3]);
        bf16x8 b = *(const bf16x8*)(mrow + ks*32);
        sacc = __builtin_amdgcn_mfma_f32_16x16x32_bf16(a, b, sacc, 0, 0, 0);
      }
      #pragma unroll
      for (int r = 0; r < 4; ++r)
        Sf[rg*16 + lhi*4 + r][ct*16 + llo] = sacc[r];
    }
  }
  __syncthreads();
  if (t < 128) {
    int row = t >> 2, h = t & 3;
    float v[19];
    float mx = -1e30f;
    #pragma unroll
    for (int c = 0; c < C_; ++c) {
      v[c] = Sf[row][h*C_ + c] + s0g[h*C_ + c];
      mx = fmaxf(mx, v[c]);
    }
    float sum = 0.f;
    #pragma unroll
    for (int c = 0; c < C_; ++c) { float e = __expf(v[c] - mx); v[c] = e; sum += e; }
    float inv = 1.f / sum;
    #pragma unroll
    for (int c = 0; c < C_; ++c) Wa[row][h*C_ + c] = f2bf(v[c] * inv);
  } else {
    int t2 = t - 128;
    int row = t2 >> 2, g4 = t2 & 3;
    #pragma unroll
    for (int j = 0; j < 5; ++j) Wa[row][CH_ + g4*5 + j] = 0;
  }
  __syncthreads();

  f32x4 oacc[16];
  #pragma unroll
  for (int i = 0; i < 16; ++i) oacc[i] = (f32x4){0.f,0.f,0.f,0.f};
  #pragma unroll
  for (int ks = 0; ks < 3; ++ks) {
    bf16x8 a = *(const bf16x8*)&Wa[rg*16 + llo][ks*32 + lhi*8];
    #pragma unroll
    for (int tile = 0; tile < 16; ++tile) {
      int n = cs*256 + tile*16 + llo;
      bf16x8 b = *(const bf16x8*)(Ut + (size_t)n*CHP_ + ks*32 + lhi*8);
      oacc[tile] = __builtin_amdgcn_mfma_f32_16x16x32_bf16(a, b, oacc[tile], 0, 0, 0);
    }
  }

  float s[4] = {0,0,0,0}, q[4] = {0,0,0,0};
  #pragma unroll
  for (int tile = 0; tile < 16; ++tile) {
    int n = cs*256 + tile*16 + llo;
    float bov = bo[n];
    #pragma unroll
    for (int r = 0; r < 4; ++r) {
      int m = rg*16 + lhi*4 + r;
      float val = oacc[tile][r] + bov + x[(size_t)(row0 + m)*D_ + n];
      oacc[tile][r] = val;
      s[r] += val;
      q[r] = fmaf(val, val, q[r]);
    }
  }
  #pragma unroll
  for (int r = 0; r < 4; ++r) {
    #pragma unroll
    for (int off = 1; off < 16; off <<= 1) {
      s[r] += __shfl_xor(s[r], off, 64);
      q[r] += __shfl_xor(q[r], off, 64);
    }
  }
  if (llo == 0) {
    #pragma unroll
    for (int r = 0; r < 4; ++r) {
      rs_[rg*16 + lhi*4 + r][cs] = s[r];
      rq_[rg*16 + lhi*4 + r][cs] = q[r];
    }
  }
  __syncthreads();
  #pragma unroll
  for (int tile = 0; tile < 16; ++tile) {
    int n = cs*256 + tile*16 + llo;
    float g = gamma[n], bt = beta[n];
    #pragma unroll
    for (int r = 0; r < 4; ++r) {
      int m = rg*16 + lhi*4 + r;
      float sum = rs_[m][0] + rs_[m][1];
      float sq  = rq_[m][0] + rq_[m][1];
      float mu  = sum * (1.f/(float)D_);
      float var = sq * (1.f/(float)D_) - mu*mu;
      float rstd = rsqrtf(var + 1e-5f);
      out[(size_t)(row0 + m)*D_ + n] = (oacc[tile][r] - mu) * rstd * g + bt;
    }
  }
}

extern "C" void kernel_launch(void* const* d_in, const int* in_sizes, int n_in,
                              void* d_out, int out_size, void* d_ws, size_t ws_size,
                              hipStream_t stream) {
  const float* x     = (const float*)d_in[0];
  const float* ce    = (const float*)d_in[1];
  const float* Wq    = (const float*)d_in[2];
  const float* bq    = (const float*)d_in[3];
  const float* Wk    = (const float*)d_in[4];
  const float* bk    = (const float*)d_in[5];
  const float* Wv    = (const float*)d_in[6];
  const float* bv    = (const float*)d_in[7];
  const float* Wo    = (const float*)d_in[8];
  const float* bo    = (const float*)d_in[9];
  const float* gamma = (const float*)d_in[10];
  const float* beta  = (const float*)d_in[11];
  float* out = (float*)d_out;

  char* ws = (char*)d_ws;
  const size_t WAG_BYTES = (size_t)NROW * CHP_ * 2;   // 12,582,912
  const size_t NEED2 = WAG_BYTES + 40960*2 + 98304*2 + 1024;

  if (ws_size >= NEED2) {
    unsigned short* WaG = (unsigned short*)ws;
    float* Kg           = (float*)(ws + WAG_BYTES);
    float* Vg           = (float*)(ws + WAG_BYTES + 40960);
    unsigned short* Mt  = (unsigned short*)(ws + WAG_BYTES + 81920);
    unsigned short* Ut  = (unsigned short*)(ws + WAG_BYTES + 81920 + 98304);
    float* s0g          = (float*)(ws + WAG_BYTES + 81920 + 196608);

    prep1<<<(2*C_*D_ + 255)/256, 256, 0, stream>>>(ce, Wk, bk, Wv, bv, Kg, Vg);
    prep2<<<CHP_, 512, 0, stream>>>(Wq, bq, Wo, Kg, Vg, Mt, Ut, s0g);
    k1_scores<<<NROW/32, 256, 0, stream>>>(x, Mt, s0g, WaG);
    k2_out<<<NROW/32, 256, 0, stream>>>(x, WaG, Ut, bo, gamma, beta, out);
  } else {
    float* Kg           = (float*)(ws);
    float* Vg           = (float*)(ws + 40960);
    unsigned short* Mt  = (unsigned short*)(ws + 81920);
    unsigned short* Ut  = (unsigned short*)(ws + 180224);
    float* s0g          = (float*)(ws + 278528);

    prep1<<<(2*C_*D_ + 255)/256, 256, 0, stream>>>(ce, Wk, bk, Wv, bv, Kg, Vg);
    prep2<<<CHP_, 512, 0, stream>>>(Wq, bq, Wo, Kg, Vg, Mt, Ut, s0g);
    fused_main<<<NROW/32, 256, 0, stream>>>(x, Mt, Ut, s0g, bo, gamma, beta, out);
  }
}

// Round 6
// 165.636 us; speedup vs baseline: 1.5653x; 1.5653x over previous
//
#include <hip/hip_runtime.h>
#include <hip/hip_bf16.h>

#define B_  32
#define P_  2048
#define C_  19
#define D_  512
#define H_  4
#define DH_ 128
#define NROW (B_*P_)
#define CH_  76          // C_*H_
#define CHP_ 96          // padded K for out-GEMM (3x32)

typedef float f32x4 __attribute__((ext_vector_type(4)));
typedef short bf16x8 __attribute__((ext_vector_type(8)));

// native cvt -> compiler emits v_cvt_pk_bf16_f32 for pairs (RNE)
__device__ __forceinline__ unsigned short f2bf(float f) {
  union { __hip_bfloat16 h; unsigned short s; } u;
  u.h = __float2bfloat16(f);
  return u.s;
}

// ---- prep1: K/V = ce @ W^T + b  (f32) ------------------------------------
__global__ __launch_bounds__(256) void prep1(
    const float* __restrict__ ce,
    const float* __restrict__ Wk, const float* __restrict__ bk,
    const float* __restrict__ Wv, const float* __restrict__ bv,
    float* __restrict__ Kg, float* __restrict__ Vg)
{
  int g = blockIdx.x * 256 + threadIdx.x;
  if (g >= 2*C_*D_) return;
  int which = (g >= C_*D_) ? 1 : 0;
  int idx = which ? (g - C_*D_) : g;
  int c = idx >> 9;
  int n = idx & (D_-1);
  const float* w = (which ? Wv : Wk) + (size_t)n * D_;
  const float* e = ce + (size_t)c * D_;
  float s = 0.f;
  #pragma unroll 8
  for (int d = 0; d < D_; ++d) s = fmaf(e[d], w[d], s);
  s += (which ? bv : bk)[n];
  if (which) Vg[idx] = s; else Kg[idx] = s;
}

// ---- prep2: M~[80][512], U_t[512][96], s0[80] -----------------------------
__global__ __launch_bounds__(512) void prep2(
    const float* __restrict__ Wq, const float* __restrict__ bq,
    const float* __restrict__ Wo,
    const float* __restrict__ Kg, const float* __restrict__ Vg,
    unsigned short* __restrict__ Mt, unsigned short* __restrict__ Ut,
    float* __restrict__ s0g)
{
  int ch = blockIdx.x;   // 0..95
  int m  = threadIdx.x;  // 0..511
  if (ch >= CH_) {
    if (ch < 80) { Mt[ch*D_ + m] = 0; if (m == 0) s0g[ch] = 0.f; }
    Ut[(size_t)m*CHP_ + ch] = 0;
    return;
  }
  int h = ch / C_, c = ch % C_;
  const float rs128 = 0.08838834764831843f;  // 1/sqrt(128)
  const float* Kr = Kg + c*D_ + h*DH_;
  const float* Vr = Vg + c*D_ + h*DH_;

  float macc = 0.f;
  #pragma unroll 4
  for (int dh = 0; dh < DH_; ++dh)
    macc = fmaf(Wq[(size_t)(h*DH_+dh)*D_ + m], Kr[dh], macc);
  Mt[ch*D_ + m] = f2bf(macc * rs128);

  float uacc = 0.f;
  const float* wor = Wo + (size_t)m*D_ + h*DH_;
  #pragma unroll 4
  for (int dh = 0; dh < DH_; ++dh)
    uacc = fmaf(wor[dh], Vr[dh], uacc);
  Ut[(size_t)m*CHP_ + ch] = f2bf(uacc);

  if (m == 0) {
    float sa = 0.f;
    const float* bqr = bq + h*DH_;
    for (int dh = 0; dh < DH_; ++dh) sa = fmaf(bqr[dh], Kr[dh], sa);
    s0g[ch] = sa * rs128;
  }
}

// ---- fused main: S = x@M~^T (+s0) -> softmax -> out = W@U + x, LN ---------
// BM=32 rows/block, 256 threads (4 waves: rg=wave>>1 row-group, cs=wave&1 col-half)
__global__ __launch_bounds__(256) void fused_main(
    const float* __restrict__ x,
    const unsigned short* __restrict__ Mt,   // [80][512] bf16 rows 76..79 zero
    const unsigned short* __restrict__ Ut,   // [512][96] bf16 cols 76..95 zero
    const float* __restrict__ s0g,           // [80]
    const float* __restrict__ bo,
    const float* __restrict__ gamma, const float* __restrict__ beta,
    float* __restrict__ out)
{
  __shared__ float Sf[32][84];
  __shared__ unsigned short Wa[32][104];
  __shared__ float rs_[32][2], rq_[32][2];

  const int t    = threadIdx.x;
  const int wave = t >> 6;
  const int lane = t & 63;
  const int lhi  = lane >> 4;
  const int llo  = lane & 15;
  const int rg   = wave >> 1;
  const int cs   = wave & 1;
  const int row0 = blockIdx.x * 32;

  // ---- phase 1: S-GEMM (K=512); cs=0 -> ct 0..2, cs=1 -> ct 3..4 ----
  {
    const float* xr = x + (size_t)(row0 + rg*16 + llo)*D_ + lhi*8;
    const int nct = cs ? 2 : 3;
    const int ct0 = cs ? 3 : 0;
    for (int i = 0; i < nct; ++i) {
      int ct = ct0 + i;
      f32x4 sacc = (f32x4){0.f,0.f,0.f,0.f};
      const unsigned short* mrow = Mt + (size_t)(ct*16 + llo)*D_ + lhi*8;
      #pragma unroll
      for (int ks = 0; ks < 16; ++ks) {
        f32x4 v0 = *(const f32x4*)(xr + ks*32);
        f32x4 v1 = *(const f32x4*)(xr + ks*32 + 4);
        bf16x8 a;
        a[0]=(short)f2bf(v0[0]); a[1]=(short)f2bf(v0[1]);
        a[2]=(short)f2bf(v0[2]); a[3]=(short)f2bf(v0[3]);
        a[4]=(short)f2bf(v1[0]); a[5]=(short)f2bf(v1[1]);
        a[6]=(short)f2bf(v1[2]); a[7]=(short)f2bf(v1[3]);
        bf16x8 b = *(const bf16x8*)(mrow + ks*32);
        sacc = __builtin_amdgcn_mfma_f32_16x16x32_bf16(a, b, sacc, 0, 0, 0);
      }
      #pragma unroll
      for (int r = 0; r < 4; ++r)
        Sf[rg*16 + lhi*4 + r][ct*16 + llo] = sacc[r];
    }
  }
  __syncthreads();

  // ---- phase 2: softmax over c per (row, h); zero pad cols 76..95 ----
  if (t < 128) {
    int row = t >> 2, h = t & 3;
    float v[19];
    float mx = -1e30f;
    #pragma unroll
    for (int c = 0; c < C_; ++c) {
      v[c] = Sf[row][h*C_ + c] + s0g[h*C_ + c];
      mx = fmaxf(mx, v[c]);
    }
    float sum = 0.f;
    #pragma unroll
    for (int c = 0; c < C_; ++c) { float e = __expf(v[c] - mx); v[c] = e; sum += e; }
    float inv = 1.f / sum;
    #pragma unroll
    for (int c = 0; c < C_; ++c) Wa[row][h*C_ + c] = f2bf(v[c] * inv);
  } else {
    int t2 = t - 128;
    int row = t2 >> 2, g4 = t2 & 3;
    #pragma unroll
    for (int j = 0; j < 5; ++j) Wa[row][CH_ + g4*5 + j] = 0;
  }
  __syncthreads();

  // ---- phase 3: out-GEMM (K=96): A = Wa rows (LDS), B = Ut rows ----
  f32x4 oacc[16];
  #pragma unroll
  for (int i = 0; i < 16; ++i) oacc[i] = (f32x4){0.f,0.f,0.f,0.f};
  #pragma unroll
  for (int ks = 0; ks < 3; ++ks) {
    bf16x8 a = *(const bf16x8*)&Wa[rg*16 + llo][ks*32 + lhi*8];
    #pragma unroll
    for (int tile = 0; tile < 16; ++tile) {
      int n = cs*256 + tile*16 + llo;
      bf16x8 b = *(const bf16x8*)(Ut + (size_t)n*CHP_ + ks*32 + lhi*8);
      oacc[tile] = __builtin_amdgcn_mfma_f32_16x16x32_bf16(a, b, oacc[tile], 0, 0, 0);
    }
  }

  // ---- phase 4: +bo, +x residual, LN (stats hoisted), store ----
  float s[4] = {0,0,0,0}, q[4] = {0,0,0,0};
  #pragma unroll
  for (int tile = 0; tile < 16; ++tile) {
    int n = cs*256 + tile*16 + llo;
    float bov = bo[n];
    #pragma unroll
    for (int r = 0; r < 4; ++r) {
      int m = rg*16 + lhi*4 + r;
      float val = oacc[tile][r] + bov + x[(size_t)(row0 + m)*D_ + n];
      oacc[tile][r] = val;
      s[r] += val;
      q[r] = fmaf(val, val, q[r]);
    }
  }
  #pragma unroll
  for (int r = 0; r < 4; ++r) {
    #pragma unroll
    for (int off = 1; off < 16; off <<= 1) {
      s[r] += __shfl_xor(s[r], off, 64);
      q[r] += __shfl_xor(q[r], off, 64);
    }
  }
  if (llo == 0) {
    #pragma unroll
    for (int r = 0; r < 4; ++r) {
      rs_[rg*16 + lhi*4 + r][cs] = s[r];
      rq_[rg*16 + lhi*4 + r][cs] = q[r];
    }
  }
  __syncthreads();
  float mu_r[4], rstd_r[4];
  #pragma unroll
  for (int r = 0; r < 4; ++r) {
    int m = rg*16 + lhi*4 + r;
    float sum = rs_[m][0] + rs_[m][1];
    float sq  = rq_[m][0] + rq_[m][1];
    float mu  = sum * (1.f/(float)D_);
    float var = sq * (1.f/(float)D_) - mu*mu;
    mu_r[r]   = mu;
    rstd_r[r] = rsqrtf(var + 1e-5f);
  }
  #pragma unroll
  for (int tile = 0; tile < 16; ++tile) {
    int n = cs*256 + tile*16 + llo;
    float g = gamma[n], bt = beta[n];
    #pragma unroll
    for (int r = 0; r < 4; ++r) {
      int m = rg*16 + lhi*4 + r;
      out[(size_t)(row0 + m)*D_ + n] = (oacc[tile][r] - mu_r[r]) * rstd_r[r] * g + bt;
    }
  }
}

extern "C" void kernel_launch(void* const* d_in, const int* in_sizes, int n_in,
                              void* d_out, int out_size, void* d_ws, size_t ws_size,
                              hipStream_t stream) {
  const float* x     = (const float*)d_in[0];
  const float* ce    = (const float*)d_in[1];
  const float* Wq    = (const float*)d_in[2];
  const float* bq    = (const float*)d_in[3];
  const float* Wk    = (const float*)d_in[4];
  const float* bk    = (const float*)d_in[5];
  const float* Wv    = (const float*)d_in[6];
  const float* bv    = (const float*)d_in[7];
  const float* Wo    = (const float*)d_in[8];
  const float* bo    = (const float*)d_in[9];
  const float* gamma = (const float*)d_in[10];
  const float* beta  = (const float*)d_in[11];
  float* out = (float*)d_out;

  char* ws = (char*)d_ws;
  float* Kg           = (float*)(ws);                   // 38912
  float* Vg           = (float*)(ws + 40960);           // 38912
  unsigned short* Mt  = (unsigned short*)(ws + 81920);  // 80*512*2 = 81920
  unsigned short* Ut  = (unsigned short*)(ws + 163840); // 512*96*2 = 98304
  float* s0g          = (float*)(ws + 262144);          // 320

  prep1<<<(2*C_*D_ + 255)/256, 256, 0, stream>>>(ce, Wk, bk, Wv, bv, Kg, Vg);
  prep2<<<CHP_, 512, 0, stream>>>(Wq, bq, Wo, Kg, Vg, Mt, Ut, s0g);
  fused_main<<<NROW/32, 256, 0, stream>>>(x, Mt, Ut, s0g, bo, gamma, beta, out);
}